// Round 3
// baseline (544.528 us; speedup 1.0000x reference)
//
#include <hip/hip_runtime.h>
#include <hip/hip_bf16.h>
#include <math.h>

#define BB 2
#define AA 120000
#define CC 80
#define K_PRE 500
#define MAX_DET 300
#define CAP 2048
#define NB2 256                       // score bins (u16-packed, 2 per u32)
#define NBW 128                       // u32 words per class histogram
#define SPEC_BIN 254                  // speculative stage threshold (bin)
#define IMQ (AA * 20)                 // 2,400,000 float4 quads per image
#define GB 1024                       // histgather blocks (512 per image)
#define GQPB 4688                     // ceil(IMQ / 512) quads per block
#define SPLIT 4                       // mask-kernel blocks per (b,c)
#define TRI_W 2304                    // triangular supT words per class

// ---------------- workspace layout (bytes) — all within proven 6,784,640 ---
#define OFF_BOXES   0
#define OFF_VALID   3840000
#define OFF_HIST    4080000
#define OFF_CNT     4161920
#define OFF_CUT     4162560
#define OFF_CAND    4163200           // 160*2048*8 = 2,621,440 -> end 6,784,640
// supT (160*2304*8 = 2,949,120 B) ALIASES the boxes region [0, 3,840,000):
// boxes are dead after k_sort; k_mask/k_greedy only read the cand slots.
#define OFF_SUPT    0
// k_sort writes its compacted outputs INTO its own (b,c) cand slot (16 KB):
//   [0, 8KB) = 512 float4 boxes; [8KB,10KB) = 512 float scores; +10KB = nv.
#define ZERO_WORDS  20640   // hist (20480 w) + cnt (160 w), contiguous

// ---------------- K1: decode + clip + valid, zero hist/cnt ----------------
__global__ __launch_bounds__(256) void k_decode(
    const float* __restrict__ deltas, const float* __restrict__ anchors,
    const int* __restrict__ ih, const int* __restrict__ iw,
    float* __restrict__ boxes, unsigned char* __restrict__ valid,
    unsigned int* __restrict__ zero_base)
{
    int tid = blockIdx.x * 256 + threadIdx.x;
    if (tid < ZERO_WORDS) zero_base[tid] = 0u;
    if (tid >= BB * AA) return;

    float4 d  = ((const float4*)deltas)[tid];
    float4 an = ((const float4*)anchors)[tid];

    const float CLAMPF = (float)4.135166556742356;  // float(log(1000/16))
    double W = (double)(*iw);
    double H = (double)(*ih);

    double aw  = (double)an.z - (double)an.x;
    double ah  = (double)an.w - (double)an.y;
    double acx = (double)an.x + 0.5 * aw;
    double acy = (double)an.y + 0.5 * ah;

    double dw = fmin((double)d.z, (double)CLAMPF);
    double dh = fmin((double)d.w, (double)CLAMPF);

    double pcx = (double)d.x * aw + acx;
    double pcy = (double)d.y * ah + acy;
    double pw  = exp(dw) * aw;
    double ph  = exp(dh) * ah;

    float x1 = (float)fmin(fmax(pcx - 0.5 * pw, 0.0), W);
    float y1 = (float)fmin(fmax(pcy - 0.5 * ph, 0.0), H);
    float x2 = (float)fmin(fmax(pcx + 0.5 * pw, 0.0), W);
    float y2 = (float)fmin(fmax(pcy + 0.5 * ph, 0.0), H);

    float4 bb; bb.x = x1; bb.y = y1; bb.z = x2; bb.w = y2;
    ((float4*)boxes)[tid] = bb;
    valid[tid] = (((x2 - x1) >= 0.01f) && ((y2 - y1) >= 0.01f)) ? 1 : 0;
}

// ---------------- K2: fused histogram + speculative gather (single pass) --
// 1024 blocks x 512 threads, unroll-8 coalesced float4 loads (128B/thread
// in flight). Histogram into 40 KB LDS (4 blocks/CU = 160 KB exact).
// Candidates with bn >= SPEC_BIN go straight to cand via global atomics.
// If the true cut for a class ends up < SPEC_BIN, k_sort's cold repair
// path (below) completes the set — exactness preserved for any input.
__global__ __launch_bounds__(512) void k_histgather(
    const float* __restrict__ scores, const unsigned char* __restrict__ valid,
    unsigned int* __restrict__ hist, unsigned int* __restrict__ cnt,
    unsigned long long* __restrict__ cand)
{
    __shared__ unsigned int lh[CC * NBW];   // 40 KB

    int blk = blockIdx.x;
    int b   = blk >> 9;               // 512 blocks per image
    int bi  = blk & 511;
    int start = b * IMQ + bi * GQPB;
    int end   = min(start + GQPB, (b + 1) * IMQ);

    for (int i = threadIdx.x; i < CC * NBW; i += 512) lh[i] = 0u;
    __syncthreads();

    const float4* s4 = (const float4*)scores;
    unsigned int* bcnt = cnt + b * CC;

    for (int i0 = start + threadIdx.x; i0 < end; i0 += 512 * 8) {
        int   ids[8];
        bool  has[8];
        float4 s[8];
        unsigned char vs[8];
        #pragma unroll
        for (int u = 0; u < 8; ++u) {
            int id = i0 + u * 512;
            has[u] = id < end;
            ids[u] = has[u] ? id : start;
        }
        #pragma unroll
        for (int u = 0; u < 8; ++u) s[u] = s4[ids[u]];
        #pragma unroll
        for (int u = 0; u < 8; ++u) vs[u] = valid[ids[u] / 20];
        #pragma unroll
        for (int u = 0; u < 8; ++u) {
            if (has[u] && vs[u]) {
                int ga = ids[u] / 20;
                int q  = ids[u] % 20;
                unsigned long long lokey =
                    (unsigned long long)(~(unsigned int)(ga - b * AA));
                float cv[4] = {s[u].x, s[u].y, s[u].z, s[u].w};
                #pragma unroll
                for (int cl = 0; cl < 4; ++cl) {
                    float sc = cv[cl];
                    if (sc > 0.05f) {
                        int bn = min((int)(sc * 256.0f), 255);
                        int c  = 4 * q + cl;
                        atomicAdd(&lh[c * NBW + (bn >> 1)], (bn & 1) ? 65536u : 1u);
                        if (bn >= SPEC_BIN) {
                            unsigned int pos = atomicAdd(&bcnt[c], 1u);
                            if (pos < CAP)
                                cand[((size_t)(b * CC + c)) * CAP + pos] =
                                    (((unsigned long long)__float_as_uint(sc)) << 32) | lokey;
                        }
                    }
                }
            }
        }
    }
    __syncthreads();

    unsigned int* gh = hist + (size_t)b * CC * NBW;
    for (int i = threadIdx.x; i < CC * NBW; i += 512) {
        unsigned int v = lh[i];
        if (v) atomicAdd(&gh[i], v);   // packed halves; totals < 65536 per half
    }
}

// ---------------- K3: find cut bin per (b,c), 256 bins -------------------
__global__ __launch_bounds__(256) void k_cut(
    const unsigned int* __restrict__ hist, int* __restrict__ cutbin)
{
    __shared__ unsigned int hw[NBW];
    __shared__ int best;
    int bc = blockIdx.x;
    int t  = threadIdx.x;
    if (t < NBW) hw[t] = hist[(size_t)bc * NBW + t];
    if (t == 0) best = 0;
    __syncthreads();
    unsigned int s = 0;
    for (int j = t; j < NB2; ++j)
        s += (hw[j >> 1] >> ((j & 1) * 16)) & 0xFFFFu;   // suffix sum at t
    if (s >= K_PRE) atomicMax(&best, t);
    __syncthreads();
    if (t == 0) cutbin[bc] = best;
}

// ---------------- K4: repair (cold) + bitonic sort + compacted write ------
// Hot path cost of repair: ONE scalar cutbin load. Cold path (cut < SPEC_BIN,
// never on this data) rescans this class's score column and appends.
// Outputs (512 boxes + scores + nv) overwrite the block's OWN cand slot
// (reads complete before writes; slots are block-exclusive).
__global__ __launch_bounds__(1024) void k_sort(
    const float* __restrict__ boxes, const float* __restrict__ scores,
    const unsigned char* __restrict__ valid, const int* __restrict__ cutbin,
    unsigned int* __restrict__ cnt, unsigned long long* __restrict__ cand)
{
    __shared__ unsigned long long kb[2][2048];   // 32 KB double buffer

    int bc = blockIdx.x;
    int b  = bc / CC;
    int c  = bc % CC;
    int i  = threadIdx.x;
    unsigned long long* cp = cand + (size_t)bc * CAP;

    int cut = cutbin[bc];
    if (cut < SPEC_BIN) {
        // cold repair: gather bn in [cut, SPEC_BIN) for this class only
        for (int a = i; a < AA; a += 1024) {
            if (valid[b * AA + a]) {
                float sc = scores[((size_t)(b * AA + a)) * CC + c];
                if (sc > 0.05f) {
                    int bn = min((int)(sc * 256.0f), 255);
                    if (bn >= cut && bn < SPEC_BIN) {
                        unsigned int pos = atomicAdd(&cnt[bc], 1u);
                        if (pos < CAP)
                            cp[pos] = (((unsigned long long)__float_as_uint(sc)) << 32)
                                      | (unsigned long long)(~(unsigned int)a);
                    }
                }
            }
        }
        __syncthreads();   // repair writes visible block-wide before n read
    }

    int n = (int)min(cnt[bc], (unsigned int)CAP);
    unsigned long long key;

    if (n <= 1024) {
        key = (i < n) ? cp[i] : 0ull;
        int p = 0;
        for (unsigned int k = 2; k <= 1024; k <<= 1) {
            bool up = ((i & k) == 0);
            for (unsigned int j = k >> 1; j > 0; j >>= 1) {
                unsigned long long other;
                if (j >= 64) {
                    kb[p][i] = key;
                    __syncthreads();
                    other = kb[p][i ^ j];
                    p ^= 1;                      // ping-pong: WAR-safe, 1 barrier/pass
                } else {
                    other = __shfl_xor(key, (int)j);
                }
                bool lower = ((i & j) == 0);
                bool keep_max = (lower == up);   // descending in "up" region
                bool mine_big = key > other;
                key = (keep_max == mine_big) ? key : other;
            }
        }
    } else {
        // 2048 fallback: 2 elements/thread (t=i and t=i+1024), hybrid passes
        unsigned long long kA = (i < n) ? cp[i] : 0ull;
        unsigned long long kB = (i + 1024 < n) ? cp[i + 1024] : 0ull;
        int tA = i, tB = i + 1024;
        int p = 0;
        for (unsigned int k = 2; k <= 2048; k <<= 1) {
            for (unsigned int j = k >> 1; j > 0; j >>= 1) {
                if (j == 1024) {
                    // partner is own pair; k=2048 => up=true, tA lower => keep max
                    unsigned long long mx = (kA > kB) ? kA : kB;
                    unsigned long long mn = (kA > kB) ? kB : kA;
                    kA = mx; kB = mn;
                } else if (j >= 64) {
                    kb[p][tA] = kA; kb[p][tB] = kB;
                    __syncthreads();
                    unsigned long long oA = kb[p][tA ^ (int)j];
                    unsigned long long oB = kb[p][tB ^ (int)j];
                    p ^= 1;
                    { bool up = ((tA & k) == 0), lo = ((tA & j) == 0);
                      bool km = (lo == up), mb = kA > oA; kA = (km == mb) ? kA : oA; }
                    { bool up = ((tB & k) == 0), lo = ((tB & j) == 0);
                      bool km = (lo == up), mb = kB > oB; kB = (km == mb) ? kB : oB; }
                } else {
                    unsigned long long oA = __shfl_xor(kA, (int)j);
                    unsigned long long oB = __shfl_xor(kB, (int)j);
                    { bool up = ((tA & k) == 0), lo = ((tA & j) == 0);
                      bool km = (lo == up), mb = kA > oA; kA = (km == mb) ? kA : oA; }
                    { bool up = ((tB & k) == 0), lo = ((tB & j) == 0);
                      bool km = (lo == up), mb = kB > oB; kB = (km == mb) ? kB : oB; }
                }
            }
        }
        key = kA;   // element i (descending) lives in kA across threads
    }

    // compacted write into OWN cand slot (boxes coalesced for mask/greedy)
    float4* sbox = (float4*)cp;            // elements [0, 1024) of slot
    float*  ssc  = (float*)(cp + 1024);    // elements [1024, 1280)
    int*    nvp  = (int*)(cp + 1280);
    if (i < 512) {
        bool v = (key != 0ull);
        float sc = v ? __uint_as_float((unsigned int)(key >> 32)) : -1.0f;
        int a = v ? (int)(~(unsigned int)key) : 0;
        float4 bb = make_float4(0.f, 0.f, 0.f, 0.f);
        if (v && i < K_PRE) bb = ((const float4*)boxes)[(size_t)b * AA + a];
        sbox[i] = bb;
        ssc[i] = sc;
    }
    if (i == 0) nvp[0] = min(n, K_PRE);
}

// ---------------- K5: suppression masks, 4 blocks per (b,c), triangular ---
// 640 blocks x 512 threads -> all 256 CUs busy. Word (j,w) exists only for
// w <= j>>6 (triangle, 2304 words/class); each word written exactly once by
// wave w of split-block s = j & 3.
__global__ __launch_bounds__(512) void k_mask(
    const unsigned long long* __restrict__ cand,
    unsigned long long* __restrict__ supTg)
{
    __shared__ float4 box4[512];    // 8 KB
    __shared__ float  ar[512];      // 2 KB

    int bc = blockIdx.x >> 2;
    int s  = blockIdx.x & (SPLIT - 1);
    int tid = threadIdx.x;
    const unsigned long long* cp = cand + (size_t)bc * CAP;

    float4 bl = ((const float4*)cp)[tid];
    box4[tid] = bl;
    float ia = (bl.z - bl.x) * (bl.w - bl.y);
    ar[tid] = ia;
    __syncthreads();

    int nv = ((const int*)(cp + 1280))[0];
    int wave = tid >> 6, lane = tid & 63;
    int ii = tid;
    float4 bi = bl;
    unsigned long long* sp = supTg + (size_t)bc * TRI_W;

    for (int j = wave * 64 + s; j < 512; j += SPLIT) {
        float4 bj = box4[j];         // wave-uniform broadcast
        float ja = ar[j];
        bool p = false;
        if (ii < j && j < nv) {
            float ltx = fmaxf(bi.x, bj.x);
            float lty = fmaxf(bi.y, bj.y);
            float rbx = fminf(bi.z, bj.z);
            float rby = fminf(bi.w, bj.w);
            float wx = fmaxf(rbx - ltx, 0.0f);
            float wy = fmaxf(rby - lty, 0.0f);
            float inter = wx * wy;
            float iou = inter / fmaxf(ia + ja - inter, 1e-9f);
            p = iou > 0.5f;
        }
        unsigned long long m = __ballot(p);
        if (lane == 0) {
            int g = j >> 6;                                  // g >= wave always
            int base = 64 * ((g * (g + 1)) >> 1) + (j & 63) * (g + 1);
            sp[base + wave] = m;
        }
    }
}

// ---------------- K6: greedy keep + compaction/output --------------------
__global__ __launch_bounds__(512) void k_greedy(
    const unsigned long long* __restrict__ cand,
    const unsigned long long* __restrict__ supTg, float* __restrict__ out)
{
    __shared__ unsigned long long supT[512 * 9];    // 36 KB (+1 pad: 4-way banks)
    __shared__ float4 box4[512];                    // 8 KB
    __shared__ float  scs[512];                     // 2 KB
    __shared__ unsigned long long keepsh[8];
    __shared__ int pfx[9];

    int bc = blockIdx.x;
    int tid = threadIdx.x;
    const unsigned long long* cp = cand + (size_t)bc * CAP;

    box4[tid] = ((const float4*)cp)[tid];
    scs[tid]  = ((const float*)(cp + 1024))[tid];
    int nv    = ((const int*)(cp + 1280))[0];

    const unsigned long long* sp = supTg + (size_t)bc * TRI_W;
    {
        int j = tid;                                 // one j per thread
        int g = j >> 6;
        int base = 64 * ((g * (g + 1)) >> 1) + (j & 63) * (g + 1);
        for (int w = 0; w <= g; ++w) supT[j * 9 + w] = sp[base + w];
    }
    __syncthreads();

    // exact greedy: word-blocked Gauss-Seidel, intra-word bounded Jacobi.
    if (tid < 64) {
        int l = tid;
        unsigned long long kept[8];
        #pragma unroll
        for (int w = 0; w < 8; ++w) {
            int j = w * 64 + l;                      // j's group g == w
            bool vj = j < nv;
            bool ext = false;
            #pragma unroll
            for (int w2 = 0; w2 < 8; ++w2)
                if (w2 < w) ext = ext || ((supT[j * 9 + w2] & kept[w2]) != 0ull);
            unsigned long long intra = supT[j * 9 + w];   // bits i<j only
            bool base = vj && !ext;
            unsigned long long kw = __ballot(base);
            for (int r = 0; r < 64; ++r) {                // depth <= 64 => exact
                bool k2 = base && ((intra & kw) == 0ull);
                unsigned long long nkw = __ballot(k2);
                if (nkw == kw) break;
                kw = nkw;
            }
            kept[w] = kw;
        }
        if (l < 8) keepsh[l] = kept[l];
    }
    __syncthreads();

    if (tid == 0) {
        int s = 0;
        for (int w = 0; w < 8; ++w) { pfx[w] = s; s += __popcll(keepsh[w]); }
        pfx[8] = s;
    }
    __syncthreads();

    // compaction: kept first (score order), then non-kept (score order)
    int total_kept = pfx[8];
    if (tid < K_PRE) {
        int t = tid;
        int w = t >> 6, bit = t & 63;
        unsigned long long kw = keepsh[w];
        bool kv = (kw >> bit) & 1ull;
        int kb2 = pfx[w] + __popcll(kw & ((bit == 0) ? 0ull : ((1ull << bit) - 1ull)));
        int p = kv ? kb2 : (total_kept + (t - kb2));
        if (p < MAX_DET) {
            float* o = out + ((size_t)bc * MAX_DET + p) * 5;
            if (kv) {
                float4 bb = box4[t];
                o[0] = bb.x; o[1] = bb.y; o[2] = bb.z; o[3] = bb.w; o[4] = scs[t];
            } else {
                o[0] = 0.f; o[1] = 0.f; o[2] = 0.f; o[3] = 0.f; o[4] = -1.0f;
            }
        }
    }
}

extern "C" void kernel_launch(void* const* d_in, const int* in_sizes, int n_in,
                              void* d_out, int out_size, void* d_ws, size_t ws_size,
                              hipStream_t stream)
{
    const float* deltas  = (const float*)d_in[0];
    const float* scores  = (const float*)d_in[1];
    const float* anchors = (const float*)d_in[2];
    const int*   ih      = (const int*)d_in[3];
    const int*   iw      = (const int*)d_in[4];
    float* out = (float*)d_out;

    char* w = (char*)d_ws;
    float*              boxes  = (float*)(w + OFF_BOXES);
    unsigned char*      valid  = (unsigned char*)(w + OFF_VALID);
    unsigned int*       hist   = (unsigned int*)(w + OFF_HIST);
    unsigned int*       cnt    = (unsigned int*)(w + OFF_CNT);
    int*                cutbin = (int*)(w + OFF_CUT);
    unsigned long long* cand   = (unsigned long long*)(w + OFF_CAND);
    unsigned long long* supTg  = (unsigned long long*)(w + OFF_SUPT);  // aliases boxes

    int g1 = (BB * AA + 255) / 256;
    k_decode<<<g1, 256, 0, stream>>>(deltas, anchors, ih, iw, boxes, valid, hist);
    k_histgather<<<GB, 512, 0, stream>>>(scores, valid, hist, cnt, cand);
    k_cut<<<BB * CC, 256, 0, stream>>>(hist, cutbin);
    k_sort<<<BB * CC, 1024, 0, stream>>>(boxes, scores, valid, cutbin, cnt, cand);
    k_mask<<<BB * CC * SPLIT, 512, 0, stream>>>(cand, supTg);
    k_greedy<<<BB * CC, 512, 0, stream>>>(cand, supTg, out);
}

// Round 4
// 225.155 us; speedup vs baseline: 2.4185x; 2.4185x over previous
//
#include <hip/hip_runtime.h>
#include <hip/hip_bf16.h>
#include <math.h>

#define BB 2
#define AA 120000
#define CC 80
#define K_PRE 500
#define MAX_DET 300
#define CAP 2048
#define NB2 256                       // score bins (u16-packed, 2 per u32)
#define NBW 128                       // u32 words per class histogram
#define SPEC_BIN 254                  // speculative stage threshold (bin)
#define HB 960                        // histgather blocks (480 per image)
#define QTOT (BB * AA * 20)           // 4,800,000 float4 quads
#define QPB (QTOT / HB)               // 5,000 quads per block
#define LBUF_G 1024                   // LDS spec-candidate staging (exp ~146/blk)
#define SPLIT 4                       // mask-kernel blocks per (b,c)
#define TRI_W 2304                    // triangular supT words per class

// ---------------- workspace layout (bytes) — all within proven 6,784,640 ---
#define OFF_BOXES   0
#define OFF_VALID   3840000
#define OFF_HIST    4080000
#define OFF_CNT     4161920
#define OFF_CUT     4162560           // (unused this round)
#define OFF_CAND    4163200           // 160*2048*8 = 2,621,440 -> end 6,784,640
// supT (160*2304*8 = 2,949,120 B) ALIASES the boxes region [0, 3,840,000):
// boxes are dead after k_sortcut; k_mask/k_greedy only read the cand slots.
#define OFF_SUPT    0
// k_sortcut writes its compacted outputs INTO its own (b,c) cand slot (16 KB):
//   words [0,1024) = 512 float4 boxes; [1024,1280) = 512 float scores; [1280] = nv.
#define ZERO_WORDS  20640   // hist (20480 w) + cnt (160 w), contiguous

// ---------------- K1: decode + clip + valid, zero hist/cnt ----------------
__global__ __launch_bounds__(256) void k_decode(
    const float* __restrict__ deltas, const float* __restrict__ anchors,
    const int* __restrict__ ih, const int* __restrict__ iw,
    float* __restrict__ boxes, unsigned char* __restrict__ valid,
    unsigned int* __restrict__ zero_base)
{
    int tid = blockIdx.x * 256 + threadIdx.x;
    if (tid < ZERO_WORDS) zero_base[tid] = 0u;
    if (tid >= BB * AA) return;

    float4 d  = ((const float4*)deltas)[tid];
    float4 an = ((const float4*)anchors)[tid];

    const float CLAMPF = (float)4.135166556742356;  // float(log(1000/16))
    double W = (double)(*iw);
    double H = (double)(*ih);

    double aw  = (double)an.z - (double)an.x;
    double ah  = (double)an.w - (double)an.y;
    double acx = (double)an.x + 0.5 * aw;
    double acy = (double)an.y + 0.5 * ah;

    double dw = fmin((double)d.z, (double)CLAMPF);
    double dh = fmin((double)d.w, (double)CLAMPF);

    double pcx = (double)d.x * aw + acx;
    double pcy = (double)d.y * ah + acy;
    double pw  = exp(dw) * aw;
    double ph  = exp(dh) * ah;

    float x1 = (float)fmin(fmax(pcx - 0.5 * pw, 0.0), W);
    float y1 = (float)fmin(fmax(pcy - 0.5 * ph, 0.0), H);
    float x2 = (float)fmin(fmax(pcx + 0.5 * pw, 0.0), W);
    float y2 = (float)fmin(fmax(pcy + 0.5 * ph, 0.0), H);

    float4 bb; bb.x = x1; bb.y = y1; bb.z = x2; bb.w = y2;
    ((float4*)boxes)[tid] = bb;
    valid[tid] = (((x2 - x1) >= 0.01f) && ((y2 - y1) >= 0.01f)) ? 1 : 0;
}

// ---------------- K2: fused histogram + spec gather, LDS-staged -----------
// Proven k_hist geometry (960 x 256, 40 KB lh) + unroll-8 loads. Spec
// candidates (bn >= SPEC_BIN) stage into LDS; ONE global atomicAdd per class
// per block at flush (the proven k_gather reservation pattern). NO contended
// global atomics in the hot loop (round-3 lesson: that cost 7x). Overflow
// spill branch (p >= LBUF_G) is exact but never taken on this data.
__global__ __launch_bounds__(256) void k_histgather(
    const float* __restrict__ scores, const unsigned char* __restrict__ valid,
    unsigned int* __restrict__ hist, unsigned int* __restrict__ cnt,
    unsigned long long* __restrict__ cand)
{
    __shared__ unsigned int lh[CC * NBW];           // 40 KB
    __shared__ unsigned long long lkey[LBUF_G];     // 8 KB
    __shared__ unsigned short lcls[LBUF_G];         // 2 KB
    __shared__ unsigned int lcnt[CC];
    __shared__ unsigned int lbase[CC];
    __shared__ unsigned int ltot;

    int blk   = blockIdx.x;
    int b     = blk / (HB / BB);
    int start = blk * QPB;
    int end   = start + QPB;

    for (int i = threadIdx.x; i < CC * NBW; i += 256) lh[i] = 0u;
    if (threadIdx.x < CC) lcnt[threadIdx.x] = 0u;
    if (threadIdx.x == 0) ltot = 0u;
    __syncthreads();

    const float4* s4 = (const float4*)scores;

    for (int i0 = start + threadIdx.x; i0 < end; i0 += 256 * 8) {
        int   ids[8];
        bool  has[8];
        float4 s[8];
        unsigned char vs[8];
        #pragma unroll
        for (int u = 0; u < 8; ++u) {
            int id = i0 + u * 256;
            has[u] = id < end;
            ids[u] = has[u] ? id : start;
        }
        #pragma unroll
        for (int u = 0; u < 8; ++u) s[u] = s4[ids[u]];
        #pragma unroll
        for (int u = 0; u < 8; ++u) vs[u] = valid[ids[u] / 20];
        #pragma unroll
        for (int u = 0; u < 8; ++u) {
            if (has[u] && vs[u]) {
                int ga = ids[u] / 20;
                int q  = ids[u] % 20;
                unsigned long long lokey =
                    (unsigned long long)(~(unsigned int)(ga - b * AA));
                float cv[4] = {s[u].x, s[u].y, s[u].z, s[u].w};
                #pragma unroll
                for (int cl = 0; cl < 4; ++cl) {
                    float sc = cv[cl];
                    if (sc > 0.05f) {
                        int bn = min((int)(sc * 256.0f), 255);
                        int c  = 4 * q + cl;
                        atomicAdd(&lh[c * NBW + (bn >> 1)], (bn & 1) ? 65536u : 1u);
                        if (bn >= SPEC_BIN) {
                            unsigned int p = atomicAdd(&ltot, 1u);
                            unsigned long long key =
                                (((unsigned long long)__float_as_uint(sc)) << 32) | lokey;
                            if (p < LBUF_G) {
                                lkey[p] = key;
                                lcls[p] = (unsigned short)c;
                                atomicAdd(&lcnt[c], 1u);
                            } else {   // exactness spill (never taken here)
                                unsigned int pos = atomicAdd(&cnt[b * CC + c], 1u);
                                if (pos < CAP)
                                    cand[((size_t)(b * CC + c)) * CAP + pos] = key;
                            }
                        }
                    }
                }
            }
        }
    }
    __syncthreads();

    unsigned int* gh = hist + (size_t)b * CC * NBW;
    for (int i = threadIdx.x; i < CC * NBW; i += 256) {
        unsigned int v = lh[i];
        if (v) atomicAdd(&gh[i], v);   // packed halves; totals < 65536 per half
    }

    if (threadIdx.x < CC) {
        unsigned int nn = lcnt[threadIdx.x];
        if (nn) lbase[threadIdx.x] = atomicAdd(&cnt[b * CC + threadIdx.x], nn);
    }
    __syncthreads();

    unsigned int tot = min(ltot, (unsigned int)LBUF_G);
    for (unsigned int i = threadIdx.x; i < tot; i += 256) {
        int c = lcls[i];
        unsigned int pos = atomicAdd(&lbase[c], 1u);
        if (pos < CAP)
            cand[((size_t)(b * CC + c)) * CAP + pos] = lkey[i];
    }
}

// ---------------- K3: fused cut + repair (cold) + sort + compact write ----
// Each block computes its own cut from hist (inlined k_cut, ~0.5 us), runs
// the cold repair if cut < SPEC_BIN (never on this data), then the hybrid
// bitonic sort. Outputs overwrite the block's OWN cand slot (all reads
// happen-before writes via the sort's barriers; proven in round 3).
__global__ __launch_bounds__(1024) void k_sortcut(
    const float* __restrict__ boxes, const float* __restrict__ scores,
    const unsigned char* __restrict__ valid, const unsigned int* __restrict__ hist,
    unsigned int* __restrict__ cnt, unsigned long long* __restrict__ cand)
{
    __shared__ unsigned long long kb[2][2048];   // 32 KB double buffer
    __shared__ unsigned int hw[NBW];
    __shared__ int best;

    int bc = blockIdx.x;
    int b  = bc / CC;
    int c  = bc % CC;
    int i  = threadIdx.x;
    unsigned long long* cp = cand + (size_t)bc * CAP;

    // ---- inline cut computation ----
    if (i < NBW) hw[i] = hist[(size_t)bc * NBW + i];
    if (i == 0) best = 0;
    __syncthreads();
    if (i < NB2) {
        unsigned int s = 0;
        for (int j = i; j < NB2; ++j)
            s += (hw[j >> 1] >> ((j & 1) * 16)) & 0xFFFFu;   // suffix sum at i
        if (s >= K_PRE) atomicMax(&best, i);
    }
    __syncthreads();
    int cut = best;

    if (cut < SPEC_BIN) {
        // cold repair: gather bn in [cut, SPEC_BIN) for this class only
        for (int a = i; a < AA; a += 1024) {
            if (valid[b * AA + a]) {
                float sc = scores[((size_t)(b * AA + a)) * CC + c];
                if (sc > 0.05f) {
                    int bn = min((int)(sc * 256.0f), 255);
                    if (bn >= cut && bn < SPEC_BIN) {
                        unsigned int pos = atomicAdd(&cnt[bc], 1u);
                        if (pos < CAP)
                            cp[pos] = (((unsigned long long)__float_as_uint(sc)) << 32)
                                      | (unsigned long long)(~(unsigned int)a);
                    }
                }
            }
        }
        __syncthreads();   // repair writes visible block-wide before n read
    }

    int n = (int)min(cnt[bc], (unsigned int)CAP);
    unsigned long long key;

    if (n <= 1024) {
        key = (i < n) ? cp[i] : 0ull;
        int p = 0;
        for (unsigned int k = 2; k <= 1024; k <<= 1) {
            bool up = ((i & k) == 0);
            for (unsigned int j = k >> 1; j > 0; j >>= 1) {
                unsigned long long other;
                if (j >= 64) {
                    kb[p][i] = key;
                    __syncthreads();
                    other = kb[p][i ^ j];
                    p ^= 1;                      // ping-pong: WAR-safe, 1 barrier/pass
                } else {
                    other = __shfl_xor(key, (int)j);
                }
                bool lower = ((i & j) == 0);
                bool keep_max = (lower == up);   // descending in "up" region
                bool mine_big = key > other;
                key = (keep_max == mine_big) ? key : other;
            }
        }
    } else {
        // 2048 fallback: 2 elements/thread (t=i and t=i+1024), hybrid passes
        unsigned long long kA = (i < n) ? cp[i] : 0ull;
        unsigned long long kB = (i + 1024 < n) ? cp[i + 1024] : 0ull;
        int tA = i, tB = i + 1024;
        int p = 0;
        for (unsigned int k = 2; k <= 2048; k <<= 1) {
            for (unsigned int j = k >> 1; j > 0; j >>= 1) {
                if (j == 1024) {
                    // partner is own pair; k=2048 => up=true, tA lower => keep max
                    unsigned long long mx = (kA > kB) ? kA : kB;
                    unsigned long long mn = (kA > kB) ? kB : kA;
                    kA = mx; kB = mn;
                } else if (j >= 64) {
                    kb[p][tA] = kA; kb[p][tB] = kB;
                    __syncthreads();
                    unsigned long long oA = kb[p][tA ^ (int)j];
                    unsigned long long oB = kb[p][tB ^ (int)j];
                    p ^= 1;
                    { bool up = ((tA & k) == 0), lo = ((tA & j) == 0);
                      bool km = (lo == up), mb = kA > oA; kA = (km == mb) ? kA : oA; }
                    { bool up = ((tB & k) == 0), lo = ((tB & j) == 0);
                      bool km = (lo == up), mb = kB > oB; kB = (km == mb) ? kB : oB; }
                } else {
                    unsigned long long oA = __shfl_xor(kA, (int)j);
                    unsigned long long oB = __shfl_xor(kB, (int)j);
                    { bool up = ((tA & k) == 0), lo = ((tA & j) == 0);
                      bool km = (lo == up), mb = kA > oA; kA = (km == mb) ? kA : oA; }
                    { bool up = ((tB & k) == 0), lo = ((tB & j) == 0);
                      bool km = (lo == up), mb = kB > oB; kB = (km == mb) ? kB : oB; }
                }
            }
        }
        key = kA;   // element i (descending) lives in kA across threads
    }

    // compacted write into OWN cand slot (boxes coalesced for mask/greedy)
    float4* sbox = (float4*)cp;            // words [0, 1024)
    float*  ssc  = (float*)(cp + 1024);    // words [1024, 1280)
    int*    nvp  = (int*)(cp + 1280);
    if (i < 512) {
        bool v = (key != 0ull);
        float sc = v ? __uint_as_float((unsigned int)(key >> 32)) : -1.0f;
        int a = v ? (int)(~(unsigned int)key) : 0;
        float4 bb = make_float4(0.f, 0.f, 0.f, 0.f);
        if (v && i < K_PRE) bb = ((const float4*)boxes)[(size_t)b * AA + a];
        sbox[i] = bb;
        ssc[i] = sc;
    }
    if (i == 0) nvp[0] = min(n, K_PRE);
}

// ---------------- K4: suppression masks, 4 blocks per (b,c), triangular ---
// 640 blocks x 512 threads -> all 256 CUs busy. Word (j,w) exists only for
// w <= j>>6 (triangle, 2304 words/class); each word written exactly once by
// wave w of split-block s = j & 3.
__global__ __launch_bounds__(512) void k_mask(
    const unsigned long long* __restrict__ cand,
    unsigned long long* __restrict__ supTg)
{
    __shared__ float4 box4[512];    // 8 KB
    __shared__ float  ar[512];      // 2 KB

    int bc = blockIdx.x >> 2;
    int s  = blockIdx.x & (SPLIT - 1);
    int tid = threadIdx.x;
    const unsigned long long* cp = cand + (size_t)bc * CAP;

    float4 bl = ((const float4*)cp)[tid];
    box4[tid] = bl;
    float ia = (bl.z - bl.x) * (bl.w - bl.y);
    ar[tid] = ia;
    __syncthreads();

    int nv = ((const int*)(cp + 1280))[0];
    int wave = tid >> 6, lane = tid & 63;
    int ii = tid;
    float4 bi = bl;
    unsigned long long* sp = supTg + (size_t)bc * TRI_W;

    for (int j = wave * 64 + s; j < 512; j += SPLIT) {
        float4 bj = box4[j];         // wave-uniform broadcast
        float ja = ar[j];
        bool p = false;
        if (ii < j && j < nv) {
            float ltx = fmaxf(bi.x, bj.x);
            float lty = fmaxf(bi.y, bj.y);
            float rbx = fminf(bi.z, bj.z);
            float rby = fminf(bi.w, bj.w);
            float wx = fmaxf(rbx - ltx, 0.0f);
            float wy = fmaxf(rby - lty, 0.0f);
            float inter = wx * wy;
            float iou = inter / fmaxf(ia + ja - inter, 1e-9f);
            p = iou > 0.5f;
        }
        unsigned long long m = __ballot(p);
        if (lane == 0) {
            int g = j >> 6;                                  // g >= wave always
            int base = 64 * ((g * (g + 1)) >> 1) + (j & 63) * (g + 1);
            sp[base + wave] = m;
        }
    }
}

// ---------------- K5: greedy keep + compaction/output --------------------
__global__ __launch_bounds__(512) void k_greedy(
    const unsigned long long* __restrict__ cand,
    const unsigned long long* __restrict__ supTg, float* __restrict__ out)
{
    __shared__ unsigned long long supT[512 * 9];    // 36 KB (+1 pad: 4-way banks)
    __shared__ float4 box4[512];                    // 8 KB
    __shared__ float  scs[512];                     // 2 KB
    __shared__ unsigned long long keepsh[8];
    __shared__ int pfx[9];

    int bc = blockIdx.x;
    int tid = threadIdx.x;
    const unsigned long long* cp = cand + (size_t)bc * CAP;

    box4[tid] = ((const float4*)cp)[tid];
    scs[tid]  = ((const float*)(cp + 1024))[tid];
    int nv    = ((const int*)(cp + 1280))[0];

    const unsigned long long* sp = supTg + (size_t)bc * TRI_W;
    {
        int j = tid;                                 // one j per thread
        int g = j >> 6;
        int base = 64 * ((g * (g + 1)) >> 1) + (j & 63) * (g + 1);
        for (int w = 0; w <= g; ++w) supT[j * 9 + w] = sp[base + w];
    }
    __syncthreads();

    // exact greedy: word-blocked Gauss-Seidel, intra-word bounded Jacobi.
    if (tid < 64) {
        int l = tid;
        unsigned long long kept[8];
        #pragma unroll
        for (int w = 0; w < 8; ++w) {
            int j = w * 64 + l;                      // j's group g == w
            bool vj = j < nv;
            bool ext = false;
            #pragma unroll
            for (int w2 = 0; w2 < 8; ++w2)
                if (w2 < w) ext = ext || ((supT[j * 9 + w2] & kept[w2]) != 0ull);
            unsigned long long intra = supT[j * 9 + w];   // bits i<j only
            bool base = vj && !ext;
            unsigned long long kw = __ballot(base);
            for (int r = 0; r < 64; ++r) {                // depth <= 64 => exact
                bool k2 = base && ((intra & kw) == 0ull);
                unsigned long long nkw = __ballot(k2);
                if (nkw == kw) break;
                kw = nkw;
            }
            kept[w] = kw;
        }
        if (l < 8) keepsh[l] = kept[l];
    }
    __syncthreads();

    if (tid == 0) {
        int s = 0;
        for (int w = 0; w < 8; ++w) { pfx[w] = s; s += __popcll(keepsh[w]); }
        pfx[8] = s;
    }
    __syncthreads();

    // compaction: kept first (score order), then non-kept (score order)
    int total_kept = pfx[8];
    if (tid < K_PRE) {
        int t = tid;
        int w = t >> 6, bit = t & 63;
        unsigned long long kw = keepsh[w];
        bool kv = (kw >> bit) & 1ull;
        int kb2 = pfx[w] + __popcll(kw & ((bit == 0) ? 0ull : ((1ull << bit) - 1ull)));
        int p = kv ? kb2 : (total_kept + (t - kb2));
        if (p < MAX_DET) {
            float* o = out + ((size_t)bc * MAX_DET + p) * 5;
            if (kv) {
                float4 bb = box4[t];
                o[0] = bb.x; o[1] = bb.y; o[2] = bb.z; o[3] = bb.w; o[4] = scs[t];
            } else {
                o[0] = 0.f; o[1] = 0.f; o[2] = 0.f; o[3] = 0.f; o[4] = -1.0f;
            }
        }
    }
}

extern "C" void kernel_launch(void* const* d_in, const int* in_sizes, int n_in,
                              void* d_out, int out_size, void* d_ws, size_t ws_size,
                              hipStream_t stream)
{
    const float* deltas  = (const float*)d_in[0];
    const float* scores  = (const float*)d_in[1];
    const float* anchors = (const float*)d_in[2];
    const int*   ih      = (const int*)d_in[3];
    const int*   iw      = (const int*)d_in[4];
    float* out = (float*)d_out;

    char* w = (char*)d_ws;
    float*              boxes  = (float*)(w + OFF_BOXES);
    unsigned char*      valid  = (unsigned char*)(w + OFF_VALID);
    unsigned int*       hist   = (unsigned int*)(w + OFF_HIST);
    unsigned int*       cnt    = (unsigned int*)(w + OFF_CNT);
    unsigned long long* cand   = (unsigned long long*)(w + OFF_CAND);
    unsigned long long* supTg  = (unsigned long long*)(w + OFF_SUPT);  // aliases boxes

    int g1 = (BB * AA + 255) / 256;
    k_decode<<<g1, 256, 0, stream>>>(deltas, anchors, ih, iw, boxes, valid, hist);
    k_histgather<<<HB, 256, 0, stream>>>(scores, valid, hist, cnt, cand);
    k_sortcut<<<BB * CC, 1024, 0, stream>>>(boxes, scores, valid, hist, cnt, cand);
    k_mask<<<BB * CC * SPLIT, 512, 0, stream>>>(cand, supTg);
    k_greedy<<<BB * CC, 512, 0, stream>>>(cand, supTg, out);
}

// Round 5
// 184.488 us; speedup vs baseline: 2.9516x; 1.2204x over previous
//
#include <hip/hip_runtime.h>
#include <hip/hip_bf16.h>
#include <math.h>

#define BB 2
#define AA 120000
#define CC 80
#define K_PRE 500
#define MAX_DET 300
#define CAP 2048
#define NB2 256                       // score bins (cold rebuild only)
#define SPEC_BIN 254                  // speculative stage threshold (bin)
#define HB 1200                       // fused blocks (600 per image)
#define QPB 4000                      // quads per block (= 200 anchors * 20)
#define APB 200                       // anchors per block
#define LBUF_G 512                    // LDS spec staging (exp ~118/blk, 30 sigma)
#define SPLIT 4                       // mask-kernel blocks per (b,c)
#define TRI_W 2304                    // triangular supT words per class

// ---------------- workspace layout (bytes) — all within proven 6,784,640 ---
#define OFF_BOXES   0
#define OFF_VALID   3840000
#define OFF_HIST    4080000           // (unused this round)
#define OFF_CNT     4161920           // 160 u32 = 640 B, zeroed via memsetAsync
#define OFF_CAND    4163200           // 160*2048*8 = 2,621,440 -> end 6,784,640
// supT (160*2304*8 = 2,949,120 B) ALIASES the boxes region [0, 3,840,000):
// boxes are dead after k_sortcut; k_mask/k_greedy only read the cand slots.
#define OFF_SUPT    0
// k_sortcut writes its compacted outputs INTO its own (b,c) cand slot (16 KB):
//   words [0,1024) = 512 float4 boxes; [1024,1280) = 512 float scores; [1280] = nv.

// ---------------- K1: fused decode + threshold scan + LDS-staged gather ---
// Each block owns 200 anchors (clean partition of the [A,C] score rows).
// Phase 1: decode its anchors (boxes+valid to global, valid to LDS).
// Phase 2: stream 4000 float4 score quads; pure-VGPR compare hot loop
// (no histogram, no per-score LDS atomic — round-4's occupancy killer).
// Candidates with bin >= SPEC_BIN stage to LDS; ONE global atomicAdd per
// class per block at flush (proven reservation pattern). Spill branch and
// k_sortcut's cold rebuild preserve exactness for arbitrary data.
__global__ __launch_bounds__(256) void k_fused(
    const float* __restrict__ deltas, const float* __restrict__ anchors,
    const float* __restrict__ scores,
    const int* __restrict__ ih, const int* __restrict__ iw,
    float* __restrict__ boxes, unsigned char* __restrict__ valid,
    unsigned int* __restrict__ cnt, unsigned long long* __restrict__ cand)
{
    __shared__ unsigned char lvalid[APB];
    __shared__ unsigned long long lkey[LBUF_G];   // 4 KB
    __shared__ unsigned short lcls[LBUF_G];       // 1 KB
    __shared__ unsigned int lcnt[CC];
    __shared__ unsigned int lbase[CC];
    __shared__ unsigned int ltot;

    int blk   = blockIdx.x;
    int b     = blk / (HB / BB);
    int abase = blk * APB;
    int start = blk * QPB;
    int end   = start + QPB;

    if (threadIdx.x < CC) lcnt[threadIdx.x] = 0u;
    if (threadIdx.x == 0) ltot = 0u;

    // ---- phase 1: decode this block's anchors ----
    if (threadIdx.x < APB) {
        int a = abase + threadIdx.x;
        float4 d  = ((const float4*)deltas)[a];
        float4 an = ((const float4*)anchors)[a];

        const float CLAMPF = (float)4.135166556742356;  // float(log(1000/16))
        double W = (double)(*iw);
        double H = (double)(*ih);

        double aw  = (double)an.z - (double)an.x;
        double ah  = (double)an.w - (double)an.y;
        double acx = (double)an.x + 0.5 * aw;
        double acy = (double)an.y + 0.5 * ah;

        double dw = fmin((double)d.z, (double)CLAMPF);
        double dh = fmin((double)d.w, (double)CLAMPF);

        double pcx = (double)d.x * aw + acx;
        double pcy = (double)d.y * ah + acy;
        double pw  = exp(dw) * aw;
        double ph  = exp(dh) * ah;

        float x1 = (float)fmin(fmax(pcx - 0.5 * pw, 0.0), W);
        float y1 = (float)fmin(fmax(pcy - 0.5 * ph, 0.0), H);
        float x2 = (float)fmin(fmax(pcx + 0.5 * pw, 0.0), W);
        float y2 = (float)fmin(fmax(pcy + 0.5 * ph, 0.0), H);

        float4 bb; bb.x = x1; bb.y = y1; bb.z = x2; bb.w = y2;
        ((float4*)boxes)[a] = bb;
        unsigned char v = (((x2 - x1) >= 0.01f) && ((y2 - y1) >= 0.01f)) ? 1 : 0;
        valid[a] = v;
        lvalid[threadIdx.x] = v;
    }
    __syncthreads();

    // ---- phase 2: threshold scan ----
    const float4* s4 = (const float4*)scores;
    const float THRF = (float)SPEC_BIN;    // bn >= SPEC_BIN  <=>  sc*256 >= THRF

    for (int i0 = start + threadIdx.x; i0 < end; i0 += 256 * 8) {
        int   ids[8];
        bool  has[8];
        float4 s[8];
        #pragma unroll
        for (int u = 0; u < 8; ++u) {
            int id = i0 + u * 256;
            has[u] = id < end;
            ids[u] = has[u] ? id : start;
        }
        #pragma unroll
        for (int u = 0; u < 8; ++u) s[u] = s4[ids[u]];
        #pragma unroll
        for (int u = 0; u < 8; ++u) {
            if (!has[u]) continue;
            float4 sv = s[u];
            float mx = fmaxf(fmaxf(sv.x, sv.y), fmaxf(sv.z, sv.w));
            if (mx * 256.0f >= THRF) {                 // rare (~4.7% of quads)
                int rel = ids[u] - start;
                int la  = rel / 20;
                if (lvalid[la]) {
                    int q = rel % 20;
                    unsigned int ai = (unsigned int)(abase + la - b * AA);
                    unsigned long long lokey = (unsigned long long)(~ai);
                    float cv[4] = {sv.x, sv.y, sv.z, sv.w};
                    #pragma unroll
                    for (int cl = 0; cl < 4; ++cl) {
                        float sc = cv[cl];
                        if (sc * 256.0f >= THRF) {
                            int c = 4 * q + cl;
                            unsigned long long key =
                                (((unsigned long long)__float_as_uint(sc)) << 32) | lokey;
                            unsigned int p = atomicAdd(&ltot, 1u);
                            if (p < LBUF_G) {
                                lkey[p] = key;
                                lcls[p] = (unsigned short)c;
                                atomicAdd(&lcnt[c], 1u);
                            } else {   // exactness spill (never taken here)
                                unsigned int pos = atomicAdd(&cnt[b * CC + c], 1u);
                                if (pos < CAP)
                                    cand[((size_t)(b * CC + c)) * CAP + pos] = key;
                            }
                        }
                    }
                }
            }
        }
    }
    __syncthreads();

    // ---- flush: one global reservation per class per block ----
    if (threadIdx.x < CC) {
        unsigned int nn = lcnt[threadIdx.x];
        if (nn) lbase[threadIdx.x] = atomicAdd(&cnt[b * CC + threadIdx.x], nn);
    }
    __syncthreads();

    unsigned int tot = min(ltot, (unsigned int)LBUF_G);
    for (unsigned int t = threadIdx.x; t < tot; t += 256) {
        int c = lcls[t];
        unsigned int pos = atomicAdd(&lbase[c], 1u);
        if (pos < CAP)
            cand[((size_t)(b * CC + c)) * CAP + pos] = lkey[t];
    }
}

// ---------------- K2: cold rebuild (exactness) + sort + compact write -----
// Hot path: read cnt, sort staged candidates, write compacted top-512 into
// the block's OWN cand slot (proven). Cold path (cnt < K_PRE or > CAP —
// never on this data): rebuild this class from raw scores with the full
// histogram+cut+gather semantics of the incumbent pipeline.
__global__ __launch_bounds__(1024) void k_sortcut(
    const float* __restrict__ boxes, const float* __restrict__ scores,
    const unsigned char* __restrict__ valid,
    const unsigned int* __restrict__ cnt, unsigned long long* __restrict__ cand)
{
    __shared__ unsigned long long kb[2][2048];   // 32 KB double buffer
    __shared__ unsigned int lh32[NB2];           // 1 KB (cold path only)
    __shared__ int best;
    __shared__ unsigned int lpos;

    int bc = blockIdx.x;
    int b  = bc / CC;
    int c  = bc % CC;
    int i  = threadIdx.x;
    unsigned long long* cp = cand + (size_t)bc * CAP;

    int n = (int)cnt[bc];    // attempt count: may exceed CAP
    if (n < K_PRE || n > CAP) {
        // ---- cold rebuild: hist -> cut -> fresh gather (incumbent semantics)
        for (int t = i; t < NB2; t += 1024) lh32[t] = 0u;
        if (i == 0) { best = 0; lpos = 0u; }
        __syncthreads();
        for (int a = i; a < AA; a += 1024) {
            if (valid[b * AA + a]) {
                float sc = scores[((size_t)(b * AA + a)) * CC + c];
                if (sc > 0.05f) {
                    int bn = min((int)(sc * 256.0f), 255);
                    atomicAdd(&lh32[bn], 1u);
                }
            }
        }
        __syncthreads();
        if (i < NB2) {
            unsigned int s = 0;
            for (int j = i; j < NB2; ++j) s += lh32[j];   // suffix sum at i
            if (s >= K_PRE) atomicMax(&best, i);
        }
        __syncthreads();
        int cut = best;
        for (int a = i; a < AA; a += 1024) {
            if (valid[b * AA + a]) {
                float sc = scores[((size_t)(b * AA + a)) * CC + c];
                if (sc > 0.05f) {
                    int bn = min((int)(sc * 256.0f), 255);
                    if (bn >= cut) {
                        unsigned int p = atomicAdd(&lpos, 1u);
                        if (p < CAP)
                            cp[p] = (((unsigned long long)__float_as_uint(sc)) << 32)
                                    | (unsigned long long)(~(unsigned int)a);
                    }
                }
            }
        }
        __syncthreads();   // global writes by this block visible block-wide
        n = (int)min(lpos, (unsigned int)CAP);
    }

    unsigned long long key;

    if (n <= 1024) {
        key = (i < n) ? cp[i] : 0ull;
        int p = 0;
        for (unsigned int k = 2; k <= 1024; k <<= 1) {
            bool up = ((i & k) == 0);
            for (unsigned int j = k >> 1; j > 0; j >>= 1) {
                unsigned long long other;
                if (j >= 64) {
                    kb[p][i] = key;
                    __syncthreads();
                    other = kb[p][i ^ j];
                    p ^= 1;                      // ping-pong: WAR-safe, 1 barrier/pass
                } else {
                    other = __shfl_xor(key, (int)j);
                }
                bool lower = ((i & j) == 0);
                bool keep_max = (lower == up);   // descending in "up" region
                bool mine_big = key > other;
                key = (keep_max == mine_big) ? key : other;
            }
        }
    } else {
        // 2048 fallback: 2 elements/thread (t=i and t=i+1024), hybrid passes
        unsigned long long kA = (i < n) ? cp[i] : 0ull;
        unsigned long long kB = (i + 1024 < n) ? cp[i + 1024] : 0ull;
        int tA = i, tB = i + 1024;
        int p = 0;
        for (unsigned int k = 2; k <= 2048; k <<= 1) {
            for (unsigned int j = k >> 1; j > 0; j >>= 1) {
                if (j == 1024) {
                    // partner is own pair; k=2048 => up=true, tA lower => keep max
                    unsigned long long mx = (kA > kB) ? kA : kB;
                    unsigned long long mn = (kA > kB) ? kB : kA;
                    kA = mx; kB = mn;
                } else if (j >= 64) {
                    kb[p][tA] = kA; kb[p][tB] = kB;
                    __syncthreads();
                    unsigned long long oA = kb[p][tA ^ (int)j];
                    unsigned long long oB = kb[p][tB ^ (int)j];
                    p ^= 1;
                    { bool up = ((tA & k) == 0), lo = ((tA & j) == 0);
                      bool km = (lo == up), mb = kA > oA; kA = (km == mb) ? kA : oA; }
                    { bool up = ((tB & k) == 0), lo = ((tB & j) == 0);
                      bool km = (lo == up), mb = kB > oB; kB = (km == mb) ? kB : oB; }
                } else {
                    unsigned long long oA = __shfl_xor(kA, (int)j);
                    unsigned long long oB = __shfl_xor(kB, (int)j);
                    { bool up = ((tA & k) == 0), lo = ((tA & j) == 0);
                      bool km = (lo == up), mb = kA > oA; kA = (km == mb) ? kA : oA; }
                    { bool up = ((tB & k) == 0), lo = ((tB & j) == 0);
                      bool km = (lo == up), mb = kB > oB; kB = (km == mb) ? kB : oB; }
                }
            }
        }
        key = kA;   // element i (descending) lives in kA across threads
    }

    // compacted write into OWN cand slot (boxes coalesced for mask/greedy)
    float4* sbox = (float4*)cp;            // words [0, 1024)
    float*  ssc  = (float*)(cp + 1024);    // words [1024, 1280)
    int*    nvp  = (int*)(cp + 1280);
    if (i < 512) {
        bool v = (key != 0ull);
        float sc = v ? __uint_as_float((unsigned int)(key >> 32)) : -1.0f;
        int a = v ? (int)(~(unsigned int)key) : 0;
        float4 bb = make_float4(0.f, 0.f, 0.f, 0.f);
        if (v && i < K_PRE) bb = ((const float4*)boxes)[(size_t)b * AA + a];
        sbox[i] = bb;
        ssc[i] = sc;
    }
    if (i == 0) nvp[0] = min(n, K_PRE);
}

// ---------------- K3: suppression masks, 4 blocks per (b,c), triangular ---
// 640 blocks x 512 threads -> all 256 CUs busy. Word (j,w) exists only for
// w <= j>>6 (triangle, 2304 words/class); each word written exactly once by
// wave w of split-block s = j & 3.
__global__ __launch_bounds__(512) void k_mask(
    const unsigned long long* __restrict__ cand,
    unsigned long long* __restrict__ supTg)
{
    __shared__ float4 box4[512];    // 8 KB
    __shared__ float  ar[512];      // 2 KB

    int bc = blockIdx.x >> 2;
    int s  = blockIdx.x & (SPLIT - 1);
    int tid = threadIdx.x;
    const unsigned long long* cp = cand + (size_t)bc * CAP;

    float4 bl = ((const float4*)cp)[tid];
    box4[tid] = bl;
    float ia = (bl.z - bl.x) * (bl.w - bl.y);
    ar[tid] = ia;
    __syncthreads();

    int nv = ((const int*)(cp + 1280))[0];
    int wave = tid >> 6, lane = tid & 63;
    int ii = tid;
    float4 bi = bl;
    unsigned long long* sp = supTg + (size_t)bc * TRI_W;

    for (int j = wave * 64 + s; j < 512; j += SPLIT) {
        float4 bj = box4[j];         // wave-uniform broadcast
        float ja = ar[j];
        bool p = false;
        if (ii < j && j < nv) {
            float ltx = fmaxf(bi.x, bj.x);
            float lty = fmaxf(bi.y, bj.y);
            float rbx = fminf(bi.z, bj.z);
            float rby = fminf(bi.w, bj.w);
            float wx = fmaxf(rbx - ltx, 0.0f);
            float wy = fmaxf(rby - lty, 0.0f);
            float inter = wx * wy;
            float iou = inter / fmaxf(ia + ja - inter, 1e-9f);
            p = iou > 0.5f;
        }
        unsigned long long m = __ballot(p);
        if (lane == 0) {
            int g = j >> 6;                                  // g >= wave always
            int base = 64 * ((g * (g + 1)) >> 1) + (j & 63) * (g + 1);
            sp[base + wave] = m;
        }
    }
}

// ---------------- K4: greedy keep + compaction/output --------------------
__global__ __launch_bounds__(512) void k_greedy(
    const unsigned long long* __restrict__ cand,
    const unsigned long long* __restrict__ supTg, float* __restrict__ out)
{
    __shared__ unsigned long long supT[512 * 9];    // 36 KB (+1 pad: 4-way banks)
    __shared__ float4 box4[512];                    // 8 KB
    __shared__ float  scs[512];                     // 2 KB
    __shared__ unsigned long long keepsh[8];
    __shared__ int pfx[9];

    int bc = blockIdx.x;
    int tid = threadIdx.x;
    const unsigned long long* cp = cand + (size_t)bc * CAP;

    box4[tid] = ((const float4*)cp)[tid];
    scs[tid]  = ((const float*)(cp + 1024))[tid];
    int nv    = ((const int*)(cp + 1280))[0];

    const unsigned long long* sp = supTg + (size_t)bc * TRI_W;
    {
        int j = tid;                                 // one j per thread
        int g = j >> 6;
        int base = 64 * ((g * (g + 1)) >> 1) + (j & 63) * (g + 1);
        for (int w = 0; w <= g; ++w) supT[j * 9 + w] = sp[base + w];
    }
    __syncthreads();

    // exact greedy: word-blocked Gauss-Seidel, intra-word bounded Jacobi.
    if (tid < 64) {
        int l = tid;
        unsigned long long kept[8];
        #pragma unroll
        for (int w = 0; w < 8; ++w) {
            int j = w * 64 + l;                      // j's group g == w
            bool vj = j < nv;
            bool ext = false;
            #pragma unroll
            for (int w2 = 0; w2 < 8; ++w2)
                if (w2 < w) ext = ext || ((supT[j * 9 + w2] & kept[w2]) != 0ull);
            unsigned long long intra = supT[j * 9 + w];   // bits i<j only
            bool base = vj && !ext;
            unsigned long long kw = __ballot(base);
            for (int r = 0; r < 64; ++r) {                // depth <= 64 => exact
                bool k2 = base && ((intra & kw) == 0ull);
                unsigned long long nkw = __ballot(k2);
                if (nkw == kw) break;
                kw = nkw;
            }
            kept[w] = kw;
        }
        if (l < 8) keepsh[l] = kept[l];
    }
    __syncthreads();

    if (tid == 0) {
        int s = 0;
        for (int w = 0; w < 8; ++w) { pfx[w] = s; s += __popcll(keepsh[w]); }
        pfx[8] = s;
    }
    __syncthreads();

    // compaction: kept first (score order), then non-kept (score order)
    int total_kept = pfx[8];
    if (tid < K_PRE) {
        int t = tid;
        int w = t >> 6, bit = t & 63;
        unsigned long long kw = keepsh[w];
        bool kv = (kw >> bit) & 1ull;
        int kb2 = pfx[w] + __popcll(kw & ((bit == 0) ? 0ull : ((1ull << bit) - 1ull)));
        int p = kv ? kb2 : (total_kept + (t - kb2));
        if (p < MAX_DET) {
            float* o = out + ((size_t)bc * MAX_DET + p) * 5;
            if (kv) {
                float4 bb = box4[t];
                o[0] = bb.x; o[1] = bb.y; o[2] = bb.z; o[3] = bb.w; o[4] = scs[t];
            } else {
                o[0] = 0.f; o[1] = 0.f; o[2] = 0.f; o[3] = 0.f; o[4] = -1.0f;
            }
        }
    }
}

extern "C" void kernel_launch(void* const* d_in, const int* in_sizes, int n_in,
                              void* d_out, int out_size, void* d_ws, size_t ws_size,
                              hipStream_t stream)
{
    const float* deltas  = (const float*)d_in[0];
    const float* scores  = (const float*)d_in[1];
    const float* anchors = (const float*)d_in[2];
    const int*   ih      = (const int*)d_in[3];
    const int*   iw      = (const int*)d_in[4];
    float* out = (float*)d_out;

    char* w = (char*)d_ws;
    float*              boxes  = (float*)(w + OFF_BOXES);
    unsigned char*      valid  = (unsigned char*)(w + OFF_VALID);
    unsigned int*       cnt    = (unsigned int*)(w + OFF_CNT);
    unsigned long long* cand   = (unsigned long long*)(w + OFF_CAND);
    unsigned long long* supTg  = (unsigned long long*)(w + OFF_SUPT);  // aliases boxes

    hipMemsetAsync(cnt, 0, BB * CC * sizeof(unsigned int), stream);
    k_fused<<<HB, 256, 0, stream>>>(deltas, anchors, scores, ih, iw,
                                    boxes, valid, cnt, cand);
    k_sortcut<<<BB * CC, 1024, 0, stream>>>(boxes, scores, valid, cnt, cand);
    k_mask<<<BB * CC * SPLIT, 512, 0, stream>>>(cand, supTg);
    k_greedy<<<BB * CC, 512, 0, stream>>>(cand, supTg, out);
}

// Round 6
// 180.522 us; speedup vs baseline: 3.0164x; 1.0220x over previous
//
#include <hip/hip_runtime.h>
#include <hip/hip_bf16.h>
#include <math.h>

#define BB 2
#define AA 120000
#define CC 80
#define K_PRE 500
#define MAX_DET 300
#define CAP 2048
#define NB2 256                       // score bins (cold rebuild only)
#define SPEC_BIN 254                  // speculative stage threshold (bin)
#define HB 1200                       // fused blocks (600 per image)
#define QPB 4000                      // quads per block (= 200 anchors * 20)
#define APB 200                       // anchors per block
#define LBUF_G 512                    // LDS spec staging (exp ~118/blk, 30 sigma)

// ---------------- workspace layout (bytes) — base region only -------------
#define OFF_BOXES   0
#define OFF_VALID   3840000
#define OFF_CNT     4161920           // 160 u32 = 640 B, zeroed via memsetAsync
#define OFF_CAND    4163200           // 160*2048*8 = 2,621,440 -> end 6,784,640
// No aliasing this round: supT lives in LDS inside k_nms2.

// ---------------- K1: fused decode + threshold scan + LDS-staged gather ---
// (unchanged from round 5 — proven at 184 us total)
__global__ __launch_bounds__(256) void k_fused(
    const float* __restrict__ deltas, const float* __restrict__ anchors,
    const float* __restrict__ scores,
    const int* __restrict__ ih, const int* __restrict__ iw,
    float* __restrict__ boxes, unsigned char* __restrict__ valid,
    unsigned int* __restrict__ cnt, unsigned long long* __restrict__ cand)
{
    __shared__ unsigned char lvalid[APB];
    __shared__ unsigned long long lkey[LBUF_G];   // 4 KB
    __shared__ unsigned short lcls[LBUF_G];       // 1 KB
    __shared__ unsigned int lcnt[CC];
    __shared__ unsigned int lbase[CC];
    __shared__ unsigned int ltot;

    int blk   = blockIdx.x;
    int b     = blk / (HB / BB);
    int abase = blk * APB;
    int start = blk * QPB;
    int end   = start + QPB;

    if (threadIdx.x < CC) lcnt[threadIdx.x] = 0u;
    if (threadIdx.x == 0) ltot = 0u;

    // ---- phase 1: decode this block's anchors ----
    if (threadIdx.x < APB) {
        int a = abase + threadIdx.x;
        float4 d  = ((const float4*)deltas)[a];
        float4 an = ((const float4*)anchors)[a];

        const float CLAMPF = (float)4.135166556742356;  // float(log(1000/16))
        double W = (double)(*iw);
        double H = (double)(*ih);

        double aw  = (double)an.z - (double)an.x;
        double ah  = (double)an.w - (double)an.y;
        double acx = (double)an.x + 0.5 * aw;
        double acy = (double)an.y + 0.5 * ah;

        double dw = fmin((double)d.z, (double)CLAMPF);
        double dh = fmin((double)d.w, (double)CLAMPF);

        double pcx = (double)d.x * aw + acx;
        double pcy = (double)d.y * ah + acy;
        double pw  = exp(dw) * aw;
        double ph  = exp(dh) * ah;

        float x1 = (float)fmin(fmax(pcx - 0.5 * pw, 0.0), W);
        float y1 = (float)fmin(fmax(pcy - 0.5 * ph, 0.0), H);
        float x2 = (float)fmin(fmax(pcx + 0.5 * pw, 0.0), W);
        float y2 = (float)fmin(fmax(pcy + 0.5 * ph, 0.0), H);

        float4 bb; bb.x = x1; bb.y = y1; bb.z = x2; bb.w = y2;
        ((float4*)boxes)[a] = bb;
        unsigned char v = (((x2 - x1) >= 0.01f) && ((y2 - y1) >= 0.01f)) ? 1 : 0;
        valid[a] = v;
        lvalid[threadIdx.x] = v;
    }
    __syncthreads();

    // ---- phase 2: threshold scan (pure-VGPR compare hot loop) ----
    const float4* s4 = (const float4*)scores;
    const float THRF = (float)SPEC_BIN;    // bn >= SPEC_BIN  <=>  sc*256 >= THRF

    for (int i0 = start + threadIdx.x; i0 < end; i0 += 256 * 8) {
        int   ids[8];
        bool  has[8];
        float4 s[8];
        #pragma unroll
        for (int u = 0; u < 8; ++u) {
            int id = i0 + u * 256;
            has[u] = id < end;
            ids[u] = has[u] ? id : start;
        }
        #pragma unroll
        for (int u = 0; u < 8; ++u) s[u] = s4[ids[u]];
        #pragma unroll
        for (int u = 0; u < 8; ++u) {
            if (!has[u]) continue;
            float4 sv = s[u];
            float mx = fmaxf(fmaxf(sv.x, sv.y), fmaxf(sv.z, sv.w));
            if (mx * 256.0f >= THRF) {                 // rare (~4.7% of quads)
                int rel = ids[u] - start;
                int la  = rel / 20;
                if (lvalid[la]) {
                    int q = rel % 20;
                    unsigned int ai = (unsigned int)(abase + la - b * AA);
                    unsigned long long lokey = (unsigned long long)(~ai);
                    float cv[4] = {sv.x, sv.y, sv.z, sv.w};
                    #pragma unroll
                    for (int cl = 0; cl < 4; ++cl) {
                        float sc = cv[cl];
                        if (sc * 256.0f >= THRF) {
                            int c = 4 * q + cl;
                            unsigned long long key =
                                (((unsigned long long)__float_as_uint(sc)) << 32) | lokey;
                            unsigned int p = atomicAdd(&ltot, 1u);
                            if (p < LBUF_G) {
                                lkey[p] = key;
                                lcls[p] = (unsigned short)c;
                                atomicAdd(&lcnt[c], 1u);
                            } else {   // exactness spill (never taken here)
                                unsigned int pos = atomicAdd(&cnt[b * CC + c], 1u);
                                if (pos < CAP)
                                    cand[((size_t)(b * CC + c)) * CAP + pos] = key;
                            }
                        }
                    }
                }
            }
        }
    }
    __syncthreads();

    // ---- flush: one global reservation per class per block ----
    if (threadIdx.x < CC) {
        unsigned int nn = lcnt[threadIdx.x];
        if (nn) lbase[threadIdx.x] = atomicAdd(&cnt[b * CC + threadIdx.x], nn);
    }
    __syncthreads();

    unsigned int tot = min(ltot, (unsigned int)LBUF_G);
    for (unsigned int t = threadIdx.x; t < tot; t += 256) {
        int c = lcls[t];
        unsigned int pos = atomicAdd(&lbase[c], 1u);
        if (pos < CAP)
            cand[((size_t)(b * CC + c)) * CAP + pos] = lkey[t];
    }
}

// ---------------- K2: fused rebuild + sort + mask + greedy + output -------
// One block per (b,c), 1024 threads. supT lives in LDS (no global round-trip,
// no extra launches). Phases: cold rebuild (never on this data) -> 10-barrier
// hybrid bitonic -> box gather -> 16-wave triangular mask -> exact greedy ->
// compaction/output. LDS ~83 KB -> 1 block/CU (160 blocks; fine).
__global__ __launch_bounds__(1024) void k_nms2(
    const float* __restrict__ boxes, const float* __restrict__ scores,
    const unsigned char* __restrict__ valid,
    const unsigned int* __restrict__ cnt, const unsigned long long* __restrict__ cand,
    float* __restrict__ out)
{
    __shared__ unsigned long long kb[2][2048];      // 32 KB double buffer (sort)
    __shared__ unsigned int lh32[NB2];              // 1 KB (cold path only)
    __shared__ int best;
    __shared__ unsigned int lpos;
    __shared__ float4 box4[512];                    // 8 KB
    __shared__ float  ar[512];                      // 2 KB
    __shared__ float  scs[512];                     // 2 KB
    __shared__ unsigned long long supT[512 * 9];    // 36 KB (+1 pad: 4-way banks)
    __shared__ unsigned long long keepsh[8];
    __shared__ int pfx[9];

    int bc = blockIdx.x;
    int b  = bc / CC;
    int c  = bc % CC;
    int i  = threadIdx.x;
    const unsigned long long* cp = cand + (size_t)bc * CAP;

    int n = (int)cnt[bc];    // attempt count: may exceed CAP
    if (n < K_PRE || n > CAP) {
        // ---- cold rebuild: hist -> cut -> fresh gather (incumbent semantics)
        unsigned long long* cpw = (unsigned long long*)cp;
        for (int t = i; t < NB2; t += 1024) lh32[t] = 0u;
        if (i == 0) { best = 0; lpos = 0u; }
        __syncthreads();
        for (int a = i; a < AA; a += 1024) {
            if (valid[b * AA + a]) {
                float sc = scores[((size_t)(b * AA + a)) * CC + c];
                if (sc > 0.05f) {
                    int bn = min((int)(sc * 256.0f), 255);
                    atomicAdd(&lh32[bn], 1u);
                }
            }
        }
        __syncthreads();
        if (i < NB2) {
            unsigned int s = 0;
            for (int j = i; j < NB2; ++j) s += lh32[j];   // suffix sum at i
            if (s >= K_PRE) atomicMax(&best, i);
        }
        __syncthreads();
        int cut = best;
        for (int a = i; a < AA; a += 1024) {
            if (valid[b * AA + a]) {
                float sc = scores[((size_t)(b * AA + a)) * CC + c];
                if (sc > 0.05f) {
                    int bn = min((int)(sc * 256.0f), 255);
                    if (bn >= cut) {
                        unsigned int p = atomicAdd(&lpos, 1u);
                        if (p < CAP)
                            cpw[p] = (((unsigned long long)__float_as_uint(sc)) << 32)
                                     | (unsigned long long)(~(unsigned int)a);
                    }
                }
            }
        }
        __syncthreads();   // this block's global writes visible block-wide
        n = (int)min(lpos, (unsigned int)CAP);
    }

    unsigned long long key;

    if (n <= 1024) {
        key = (i < n) ? cp[i] : 0ull;
        int p = 0;
        for (unsigned int k = 2; k <= 1024; k <<= 1) {
            bool up = ((i & k) == 0);
            for (unsigned int j = k >> 1; j > 0; j >>= 1) {
                unsigned long long other;
                if (j >= 64) {
                    kb[p][i] = key;
                    __syncthreads();
                    other = kb[p][i ^ j];
                    p ^= 1;                      // ping-pong: WAR-safe, 1 barrier/pass
                } else {
                    other = __shfl_xor(key, (int)j);
                }
                bool lower = ((i & j) == 0);
                bool keep_max = (lower == up);   // descending in "up" region
                bool mine_big = key > other;
                key = (keep_max == mine_big) ? key : other;
            }
        }
    } else {
        // 2048 fallback: 2 elements/thread (t=i and t=i+1024), hybrid passes
        unsigned long long kA = (i < n) ? cp[i] : 0ull;
        unsigned long long kB = (i + 1024 < n) ? cp[i + 1024] : 0ull;
        int tA = i, tB = i + 1024;
        int p = 0;
        for (unsigned int k = 2; k <= 2048; k <<= 1) {
            for (unsigned int j = k >> 1; j > 0; j >>= 1) {
                if (j == 1024) {
                    // partner is own pair; k=2048 => up=true, tA lower => keep max
                    unsigned long long mx = (kA > kB) ? kA : kB;
                    unsigned long long mn = (kA > kB) ? kB : kA;
                    kA = mx; kB = mn;
                } else if (j >= 64) {
                    kb[p][tA] = kA; kb[p][tB] = kB;
                    __syncthreads();
                    unsigned long long oA = kb[p][tA ^ (int)j];
                    unsigned long long oB = kb[p][tB ^ (int)j];
                    p ^= 1;
                    { bool up = ((tA & k) == 0), lo = ((tA & j) == 0);
                      bool km = (lo == up), mb = kA > oA; kA = (km == mb) ? kA : oA; }
                    { bool up = ((tB & k) == 0), lo = ((tB & j) == 0);
                      bool km = (lo == up), mb = kB > oB; kB = (km == mb) ? kB : oB; }
                } else {
                    unsigned long long oA = __shfl_xor(kA, (int)j);
                    unsigned long long oB = __shfl_xor(kB, (int)j);
                    { bool up = ((tA & k) == 0), lo = ((tA & j) == 0);
                      bool km = (lo == up), mb = kA > oA; kA = (km == mb) ? kA : oA; }
                    { bool up = ((tB & k) == 0), lo = ((tB & j) == 0);
                      bool km = (lo == up), mb = kB > oB; kB = (km == mb) ? kB : oB; }
                }
            }
        }
        key = kA;   // element i (descending) lives in kA across threads
    }

    // ---- box gather into LDS ----
    if (i < 512) {
        bool v = (key != 0ull);
        scs[i] = v ? __uint_as_float((unsigned int)(key >> 32)) : -1.0f;
        int a = v ? (int)(~(unsigned int)key) : 0;
        float4 bb = make_float4(0.f, 0.f, 0.f, 0.f);
        if (v && i < K_PRE) bb = ((const float4*)boxes)[(size_t)b * AA + a];
        box4[i] = bb;
        ar[i] = (bb.z - bb.x) * (bb.w - bb.y);
    }
    __syncthreads();

    int nv = min(n, K_PRE);

    // ---- 16-wave triangular mask, LDS-resident supT ----
    // Word (j, iw) written exactly once (by wave j%16 at i-word iw, only for
    // j >= iw*64 i.e. iw <= j>>6) — exactly the set greedy reads; no zeroing.
    {
        int wave = threadIdx.x >> 6;
        int lane = threadIdx.x & 63;
        for (int iw = 0; iw < 8; ++iw) {
            int ii = iw * 64 + lane;
            float4 bi = box4[ii];
            float ia = ar[ii];
            for (int j = iw * 64 + wave; j < 512; j += 16) {
                float4 bj = box4[j];    // wave-uniform broadcast
                float ja = ar[j];       // broadcast
                bool p = false;
                if (ii < j && j < nv) {
                    float ltx = fmaxf(bi.x, bj.x);
                    float lty = fmaxf(bi.y, bj.y);
                    float rbx = fminf(bi.z, bj.z);
                    float rby = fminf(bi.w, bj.w);
                    float wx = fmaxf(rbx - ltx, 0.0f);
                    float wy = fmaxf(rby - lty, 0.0f);
                    float inter = wx * wy;
                    float iou = inter / fmaxf(ia + ja - inter, 1e-9f);
                    p = iou > 0.5f;
                }
                unsigned long long m = __ballot(p);
                if (lane == 0) supT[j * 9 + iw] = m;
            }
        }
    }
    __syncthreads();

    // ---- exact greedy: word-blocked Gauss-Seidel, intra-word Jacobi ----
    if (threadIdx.x < 64) {
        int l = threadIdx.x;
        unsigned long long kept[8];
        #pragma unroll
        for (int w = 0; w < 8; ++w) {
            int j = w * 64 + l;
            bool vj = j < nv;
            bool ext = false;
            #pragma unroll
            for (int w2 = 0; w2 < 8; ++w2)
                if (w2 < w) ext = ext || ((supT[j * 9 + w2] & kept[w2]) != 0ull);
            unsigned long long intra = supT[j * 9 + w];   // bits i<j only
            bool base = vj && !ext;
            unsigned long long kw = __ballot(base);
            for (int r = 0; r < 64; ++r) {                // depth <= 64 => exact
                bool k2 = base && ((intra & kw) == 0ull);
                unsigned long long nkw = __ballot(k2);
                if (nkw == kw) break;
                kw = nkw;
            }
            kept[w] = kw;
        }
        if (l < 8) keepsh[l] = kept[l];
    }
    __syncthreads();

    if (threadIdx.x == 0) {
        int s = 0;
        for (int w = 0; w < 8; ++w) { pfx[w] = s; s += __popcll(keepsh[w]); }
        pfx[8] = s;
    }
    __syncthreads();

    // ---- compaction: kept first (score order), then non-kept ----
    int total_kept = pfx[8];
    if (threadIdx.x < K_PRE) {
        int t = threadIdx.x;
        int w = t >> 6, bit = t & 63;
        unsigned long long kw = keepsh[w];
        bool kv = (kw >> bit) & 1ull;
        int kb2 = pfx[w] + __popcll(kw & ((bit == 0) ? 0ull : ((1ull << bit) - 1ull)));
        int p = kv ? kb2 : (total_kept + (t - kb2));
        if (p < MAX_DET) {
            float* o = out + ((size_t)bc * MAX_DET + p) * 5;
            if (kv) {
                float4 bb = box4[t];
                o[0] = bb.x; o[1] = bb.y; o[2] = bb.z; o[3] = bb.w; o[4] = scs[t];
            } else {
                o[0] = 0.f; o[1] = 0.f; o[2] = 0.f; o[3] = 0.f; o[4] = -1.0f;
            }
        }
    }
}

extern "C" void kernel_launch(void* const* d_in, const int* in_sizes, int n_in,
                              void* d_out, int out_size, void* d_ws, size_t ws_size,
                              hipStream_t stream)
{
    const float* deltas  = (const float*)d_in[0];
    const float* scores  = (const float*)d_in[1];
    const float* anchors = (const float*)d_in[2];
    const int*   ih      = (const int*)d_in[3];
    const int*   iw      = (const int*)d_in[4];
    float* out = (float*)d_out;

    char* w = (char*)d_ws;
    float*              boxes  = (float*)(w + OFF_BOXES);
    unsigned char*      valid  = (unsigned char*)(w + OFF_VALID);
    unsigned int*       cnt    = (unsigned int*)(w + OFF_CNT);
    unsigned long long* cand   = (unsigned long long*)(w + OFF_CAND);

    hipMemsetAsync(cnt, 0, BB * CC * sizeof(unsigned int), stream);
    k_fused<<<HB, 256, 0, stream>>>(deltas, anchors, scores, ih, iw,
                                    boxes, valid, cnt, cand);
    k_nms2<<<BB * CC, 1024, 0, stream>>>(boxes, scores, valid, cnt, cand, out);
}

// Round 8
// 175.593 us; speedup vs baseline: 3.1011x; 1.0281x over previous
//
#include <hip/hip_runtime.h>
#include <hip/hip_bf16.h>
#include <math.h>

#define BB 2
#define AA 120000
#define CC 80
#define K_PRE 500
#define MAX_DET 300
#define CAP 2048
#define NB2 256                       // score bins (cold rebuild only)
#define SPEC_BIN 254                  // speculative stage threshold (bin)
#define HB 1200                       // fused blocks (600 per image)
#define QPB 4000                      // quads per block (= 200 anchors * 20)
#define APB 200                       // anchors per block
#define LBUF_G 512                    // LDS spec staging (exp ~118/blk, 30 sigma)

// ---------------- workspace layout (bytes) — base region only -------------
#define OFF_BOXES   0
#define OFF_VALID   3840000
#define OFF_CNT     4161920           // 160 u32 = 640 B, zeroed via memsetAsync
#define OFF_CAND    4163200           // 160*2048*8 = 2,621,440 -> end 6,784,640

// ---------------- K1: fused decode + threshold scan + LDS-staged gather ---
// (byte-identical to the round-6 proven kernel)
__global__ __launch_bounds__(256) void k_fused(
    const float* __restrict__ deltas, const float* __restrict__ anchors,
    const float* __restrict__ scores,
    const int* __restrict__ ih, const int* __restrict__ iw,
    float* __restrict__ boxes, unsigned char* __restrict__ valid,
    unsigned int* __restrict__ cnt, unsigned long long* __restrict__ cand)
{
    __shared__ unsigned char lvalid[APB];
    __shared__ unsigned long long lkey[LBUF_G];   // 4 KB
    __shared__ unsigned short lcls[LBUF_G];       // 1 KB
    __shared__ unsigned int lcnt[CC];
    __shared__ unsigned int lbase[CC];
    __shared__ unsigned int ltot;

    int blk   = blockIdx.x;
    int b     = blk / (HB / BB);
    int abase = blk * APB;
    int start = blk * QPB;
    int end   = start + QPB;

    if (threadIdx.x < CC) lcnt[threadIdx.x] = 0u;
    if (threadIdx.x == 0) ltot = 0u;

    // ---- phase 1: decode this block's anchors ----
    if (threadIdx.x < APB) {
        int a = abase + threadIdx.x;
        float4 d  = ((const float4*)deltas)[a];
        float4 an = ((const float4*)anchors)[a];

        const float CLAMPF = (float)4.135166556742356;  // float(log(1000/16))
        double W = (double)(*iw);
        double H = (double)(*ih);

        double aw  = (double)an.z - (double)an.x;
        double ah  = (double)an.w - (double)an.y;
        double acx = (double)an.x + 0.5 * aw;
        double acy = (double)an.y + 0.5 * ah;

        double dw = fmin((double)d.z, (double)CLAMPF);
        double dh = fmin((double)d.w, (double)CLAMPF);

        double pcx = (double)d.x * aw + acx;
        double pcy = (double)d.y * ah + acy;
        double pw  = exp(dw) * aw;
        double ph  = exp(dh) * ah;

        float x1 = (float)fmin(fmax(pcx - 0.5 * pw, 0.0), W);
        float y1 = (float)fmin(fmax(pcy - 0.5 * ph, 0.0), H);
        float x2 = (float)fmin(fmax(pcx + 0.5 * pw, 0.0), W);
        float y2 = (float)fmin(fmax(pcy + 0.5 * ph, 0.0), H);

        float4 bb; bb.x = x1; bb.y = y1; bb.z = x2; bb.w = y2;
        ((float4*)boxes)[a] = bb;
        unsigned char v = (((x2 - x1) >= 0.01f) && ((y2 - y1) >= 0.01f)) ? 1 : 0;
        valid[a] = v;
        lvalid[threadIdx.x] = v;
    }
    __syncthreads();

    // ---- phase 2: threshold scan (pure-VGPR compare hot loop) ----
    const float4* s4 = (const float4*)scores;
    const float THRF = (float)SPEC_BIN;    // bn >= SPEC_BIN  <=>  sc*256 >= THRF

    for (int i0 = start + threadIdx.x; i0 < end; i0 += 256 * 8) {
        int   ids[8];
        bool  has[8];
        float4 s[8];
        #pragma unroll
        for (int u = 0; u < 8; ++u) {
            int id = i0 + u * 256;
            has[u] = id < end;
            ids[u] = has[u] ? id : start;
        }
        #pragma unroll
        for (int u = 0; u < 8; ++u) s[u] = s4[ids[u]];
        #pragma unroll
        for (int u = 0; u < 8; ++u) {
            if (!has[u]) continue;
            float4 sv = s[u];
            float mx = fmaxf(fmaxf(sv.x, sv.y), fmaxf(sv.z, sv.w));
            if (mx * 256.0f >= THRF) {                 // rare (~4.7% of quads)
                int rel = ids[u] - start;
                int la  = rel / 20;
                if (lvalid[la]) {
                    int q = rel % 20;
                    unsigned int ai = (unsigned int)(abase + la - b * AA);
                    unsigned long long lokey = (unsigned long long)(~ai);
                    float cv[4] = {sv.x, sv.y, sv.z, sv.w};
                    #pragma unroll
                    for (int cl = 0; cl < 4; ++cl) {
                        float sc = cv[cl];
                        if (sc * 256.0f >= THRF) {
                            int c = 4 * q + cl;
                            unsigned long long key =
                                (((unsigned long long)__float_as_uint(sc)) << 32) | lokey;
                            unsigned int p = atomicAdd(&ltot, 1u);
                            if (p < LBUF_G) {
                                lkey[p] = key;
                                lcls[p] = (unsigned short)c;
                                atomicAdd(&lcnt[c], 1u);
                            } else {   // exactness spill (never taken here)
                                unsigned int pos = atomicAdd(&cnt[b * CC + c], 1u);
                                if (pos < CAP)
                                    cand[((size_t)(b * CC + c)) * CAP + pos] = key;
                            }
                        }
                    }
                }
            }
        }
    }
    __syncthreads();

    // ---- flush: one global reservation per class per block ----
    if (threadIdx.x < CC) {
        unsigned int nn = lcnt[threadIdx.x];
        if (nn) lbase[threadIdx.x] = atomicAdd(&cnt[b * CC + threadIdx.x], nn);
    }
    __syncthreads();

    unsigned int tot = min(ltot, (unsigned int)LBUF_G);
    for (unsigned int t = threadIdx.x; t < tot; t += 256) {
        int c = lcls[t];
        unsigned int pos = atomicAdd(&lbase[c], 1u);
        if (pos < CAP)
            cand[((size_t)(b * CC + c)) * CAP + pos] = lkey[t];
    }
}

// ---------------- K2: fused rebuild + sort + mask + greedy + output -------
// One block per (b,c), 1024 threads, supT in LDS. Changes vs round 6:
// (1) division-free IoU predicate — inter/den > 0.5 decided by the exact
//     Sterbenz difference inter - 0.5*den outside a 2^-20 relative band
//     (16x wider than the div half-ulp window); inside the band the real
//     f32 division is replayed => bit-identical decisions.
// (2) mask loop bound j < nv; greedy vj-guards every supT read for j >= nv.
__global__ __launch_bounds__(1024) void k_nms2(
    const float* __restrict__ boxes, const float* __restrict__ scores,
    const unsigned char* __restrict__ valid,
    const unsigned int* __restrict__ cnt, const unsigned long long* __restrict__ cand,
    float* __restrict__ out)
{
    __shared__ unsigned long long kb[2][2048];      // 32 KB double buffer (sort)
    __shared__ unsigned int lh32[NB2];              // 1 KB (cold path only)
    __shared__ int best;
    __shared__ unsigned int lpos;
    __shared__ float4 box4[512];                    // 8 KB
    __shared__ float  ar[512];                      // 2 KB
    __shared__ float  scs[512];                     // 2 KB
    __shared__ unsigned long long supT[512 * 9];    // 36 KB (+1 pad: 4-way banks)
    __shared__ unsigned long long keepsh[8];
    __shared__ int pfx[9];

    int bc = blockIdx.x;
    int b  = bc / CC;
    int c  = bc % CC;
    int i  = threadIdx.x;
    const unsigned long long* cp = cand + (size_t)bc * CAP;

    int n = (int)cnt[bc];    // attempt count: may exceed CAP
    if (n < K_PRE || n > CAP) {
        // ---- cold rebuild: hist -> cut -> fresh gather (incumbent semantics)
        unsigned long long* cpw = (unsigned long long*)cp;
        for (int t = i; t < NB2; t += 1024) lh32[t] = 0u;
        if (i == 0) { best = 0; lpos = 0u; }
        __syncthreads();
        for (int a = i; a < AA; a += 1024) {
            if (valid[b * AA + a]) {
                float sc = scores[((size_t)(b * AA + a)) * CC + c];
                if (sc > 0.05f) {
                    int bn = min((int)(sc * 256.0f), 255);
                    atomicAdd(&lh32[bn], 1u);
                }
            }
        }
        __syncthreads();
        if (i < NB2) {
            unsigned int s = 0;
            for (int j = i; j < NB2; ++j) s += lh32[j];   // suffix sum at i
            if (s >= K_PRE) atomicMax(&best, i);
        }
        __syncthreads();
        int cut = best;
        for (int a = i; a < AA; a += 1024) {
            if (valid[b * AA + a]) {
                float sc = scores[((size_t)(b * AA + a)) * CC + c];
                if (sc > 0.05f) {
                    int bn = min((int)(sc * 256.0f), 255);
                    if (bn >= cut) {
                        unsigned int p = atomicAdd(&lpos, 1u);
                        if (p < CAP)
                            cpw[p] = (((unsigned long long)__float_as_uint(sc)) << 32)
                                     | (unsigned long long)(~(unsigned int)a);
                    }
                }
            }
        }
        __syncthreads();   // this block's global writes visible block-wide
        n = (int)min(lpos, (unsigned int)CAP);
    }

    unsigned long long key;

    if (n <= 1024) {
        key = (i < n) ? cp[i] : 0ull;
        int p = 0;
        for (unsigned int k = 2; k <= 1024; k <<= 1) {
            bool up = ((i & k) == 0);
            for (unsigned int j = k >> 1; j > 0; j >>= 1) {
                unsigned long long other;
                if (j >= 64) {
                    kb[p][i] = key;
                    __syncthreads();
                    other = kb[p][i ^ j];
                    p ^= 1;                      // ping-pong: WAR-safe, 1 barrier/pass
                } else {
                    other = __shfl_xor(key, (int)j);
                }
                bool lower = ((i & j) == 0);
                bool keep_max = (lower == up);   // descending in "up" region
                bool mine_big = key > other;
                key = (keep_max == mine_big) ? key : other;
            }
        }
    } else {
        // 2048 fallback: 2 elements/thread (t=i and t=i+1024), hybrid passes
        unsigned long long kA = (i < n) ? cp[i] : 0ull;
        unsigned long long kB = (i + 1024 < n) ? cp[i + 1024] : 0ull;
        int tA = i, tB = i + 1024;
        int p = 0;
        for (unsigned int k = 2; k <= 2048; k <<= 1) {
            for (unsigned int j = k >> 1; j > 0; j >>= 1) {
                if (j == 1024) {
                    // partner is own pair; k=2048 => up=true, tA lower => keep max
                    unsigned long long mx = (kA > kB) ? kA : kB;
                    unsigned long long mn = (kA > kB) ? kB : kA;
                    kA = mx; kB = mn;
                } else if (j >= 64) {
                    kb[p][tA] = kA; kb[p][tB] = kB;
                    __syncthreads();
                    unsigned long long oA = kb[p][tA ^ (int)j];
                    unsigned long long oB = kb[p][tB ^ (int)j];
                    p ^= 1;
                    { bool up = ((tA & k) == 0), lo = ((tA & j) == 0);
                      bool km = (lo == up), mb = kA > oA; kA = (km == mb) ? kA : oA; }
                    { bool up = ((tB & k) == 0), lo = ((tB & j) == 0);
                      bool km = (lo == up), mb = kB > oB; kB = (km == mb) ? kB : oB; }
                } else {
                    unsigned long long oA = __shfl_xor(kA, (int)j);
                    unsigned long long oB = __shfl_xor(kB, (int)j);
                    { bool up = ((tA & k) == 0), lo = ((tA & j) == 0);
                      bool km = (lo == up), mb = kA > oA; kA = (km == mb) ? kA : oA; }
                    { bool up = ((tB & k) == 0), lo = ((tB & j) == 0);
                      bool km = (lo == up), mb = kB > oB; kB = (km == mb) ? kB : oB; }
                }
            }
        }
        key = kA;   // element i (descending) lives in kA across threads
    }

    // ---- box gather into LDS ----
    if (i < 512) {
        bool v = (key != 0ull);
        scs[i] = v ? __uint_as_float((unsigned int)(key >> 32)) : -1.0f;
        int a = v ? (int)(~(unsigned int)key) : 0;
        float4 bb = make_float4(0.f, 0.f, 0.f, 0.f);
        if (v && i < K_PRE) bb = ((const float4*)boxes)[(size_t)b * AA + a];
        box4[i] = bb;
        ar[i] = (bb.z - bb.x) * (bb.w - bb.y);
    }
    __syncthreads();

    int nv = min(n, K_PRE);

    // ---- 16-wave triangular mask, LDS-resident supT, division-free -------
    {
        int wave = threadIdx.x >> 6;
        int lane = threadIdx.x & 63;
        for (int iw = 0; iw < 8; ++iw) {
            int ii = iw * 64 + lane;
            float4 bi = box4[ii];
            float ia = ar[ii];
            for (int j = iw * 64 + wave; j < nv; j += 16) {
                float4 bj = box4[j];    // wave-uniform broadcast
                float ja = ar[j];       // broadcast
                bool p = false;
                if (ii < j) {
                    float ltx = fmaxf(bi.x, bj.x);
                    float lty = fmaxf(bi.y, bj.y);
                    float rbx = fminf(bi.z, bj.z);
                    float rby = fminf(bi.w, bj.w);
                    float wx = fmaxf(rbx - ltx, 0.0f);
                    float wy = fmaxf(rby - lty, 0.0f);
                    float inter = wx * wy;
                    float den = fmaxf(ia + ja - inter, 1e-9f);
                    float h   = 0.5f * den;          // exact (exponent decrement)
                    float diff = inter - h;          // exact near boundary (Sterbenz)
                    if (fabsf(diff) > h * 9.5367431640625e-07f) {
                        p = diff > 0.0f;             // provably == (inter/den > 0.5)
                    } else {
                        p = (inter / den) > 0.5f;    // vanishing band: replay division
                    }
                }
                unsigned long long m = __ballot(p);
                if (lane == 0) supT[j * 9 + iw] = m;
            }
        }
    }
    __syncthreads();

    // ---- exact greedy: word-blocked Gauss-Seidel, intra-word Jacobi ----
    // (vj guards every supT read: words for j >= nv were not written)
    if (threadIdx.x < 64) {
        int l = threadIdx.x;
        unsigned long long kept[8];
        #pragma unroll
        for (int w = 0; w < 8; ++w) {
            int j = w * 64 + l;
            bool vj = j < nv;
            bool ext = false;
            #pragma unroll
            for (int w2 = 0; w2 < 8; ++w2)
                if (w2 < w) ext = ext || (vj && (supT[j * 9 + w2] & kept[w2]) != 0ull);
            unsigned long long intra = vj ? supT[j * 9 + w] : 0ull;  // bits i<j only
            bool base = vj && !ext;
            unsigned long long kw = __ballot(base);
            for (int r = 0; r < 64; ++r) {                // depth <= 64 => exact
                bool k2 = base && ((intra & kw) == 0ull);
                unsigned long long nkw = __ballot(k2);
                if (nkw == kw) break;
                kw = nkw;
            }
            kept[w] = kw;
        }
        if (l < 8) keepsh[l] = kept[l];
    }
    __syncthreads();

    if (threadIdx.x == 0) {
        int s = 0;
        for (int w = 0; w < 8; ++w) { pfx[w] = s; s += __popcll(keepsh[w]); }
        pfx[8] = s;
    }
    __syncthreads();

    // ---- compaction: kept first (score order), then non-kept ----
    int total_kept = pfx[8];
    if (threadIdx.x < K_PRE) {
        int t = threadIdx.x;
        int w = t >> 6, bit = t & 63;
        unsigned long long kw = keepsh[w];
        bool kv = (kw >> bit) & 1ull;
        int kb2 = pfx[w] + __popcll(kw & ((bit == 0) ? 0ull : ((1ull << bit) - 1ull)));
        int p = kv ? kb2 : (total_kept + (t - kb2));
        if (p < MAX_DET) {
            float* o = out + ((size_t)bc * MAX_DET + p) * 5;
            if (kv) {
                float4 bb = box4[t];
                o[0] = bb.x; o[1] = bb.y; o[2] = bb.z; o[3] = bb.w; o[4] = scs[t];
            } else {
                o[0] = 0.f; o[1] = 0.f; o[2] = 0.f; o[3] = 0.f; o[4] = -1.0f;
            }
        }
    }
}

extern "C" void kernel_launch(void* const* d_in, const int* in_sizes, int n_in,
                              void* d_out, int out_size, void* d_ws, size_t ws_size,
                              hipStream_t stream)
{
    const float* deltas  = (const float*)d_in[0];
    const float* scores  = (const float*)d_in[1];
    const float* anchors = (const float*)d_in[2];
    const int*   ih      = (const int*)d_in[3];
    const int*   iw      = (const int*)d_in[4];
    float* out = (float*)d_out;

    char* w = (char*)d_ws;
    float*              boxes  = (float*)(w + OFF_BOXES);
    unsigned char*      valid  = (unsigned char*)(w + OFF_VALID);
    unsigned int*       cnt    = (unsigned int*)(w + OFF_CNT);
    unsigned long long* cand   = (unsigned long long*)(w + OFF_CAND);

    hipMemsetAsync(cnt, 0, BB * CC * sizeof(unsigned int), stream);
    k_fused<<<HB, 256, 0, stream>>>(deltas, anchors, scores, ih, iw,
                                    boxes, valid, cnt, cand);
    k_nms2<<<BB * CC, 1024, 0, stream>>>(boxes, scores, valid, cnt, cand, out);
}